// Round 1
// baseline (10029.334 us; speedup 1.0000x reference)
//
#include <hip/hip_runtime.h>
#include <math.h>

// TopDownNet: N=131072 samples, K=10 sequential steps, hidden=256, n_in=14.
// fp32 vector-ALU (threshold 2.17e-5 forbids bf16 MFMA through the recurrence).
// Block = 256 threads = 32 samples persistent across the scan.
// Wave w owns samples w*8..w*8+7; lane l owns neuron columns l*4..l*4+3.
// Per input row i: 32 FMAs/lane vs 2 broadcast ds_read_b128 + 1 coalesced
// global_load_dwordx4 (weights from L2, shared by all blocks) -> VALU-bound.

constexpr int NH    = 256;   // hidden width
constexpr int NIN   = 14;    // tower features
constexpr int KS    = 10;    // scan steps
constexpr int NSAMP = 32;    // samples per block
constexpr int TS    = 8;     // samples per wave
constexpr int TN    = 4;     // neuron cols per lane
constexpr int SROW  = 36;    // LDS row stride in floats (16B aligned, de-aliases banks)
constexpr int BUF   = NH * SROW;                 // one 256x32 activation buffer
constexpr size_t SMEM_BYTES = (size_t)(2 * BUF + NIN * SROW) * sizeof(float); // 75744 B

__device__ __forceinline__ void zero_acc(float acc[TS][TN]) {
#pragma unroll
  for (int s = 0; s < TS; ++s)
#pragma unroll
    for (int j = 0; j < TN; ++j) acc[s][j] = 0.f;
}

// acc[s][j] += sum_i X[i][scol+s] * W[wrow0+i][l*4+j]
template <int ROWS>
__device__ __forceinline__ void gemm_part(float acc[TS][TN],
                                          const float* __restrict__ X,
                                          const float* __restrict__ Wg,
                                          int wrow0, int l, int scol) {
  const float4* __restrict__ Wp =
      reinterpret_cast<const float4*>(Wg) + wrow0 * (NH / 4) + l;
#pragma unroll 4
  for (int i = 0; i < ROWS; ++i) {
    float4 wv = Wp[i * (NH / 4)];                                   // global, coalesced 16B/lane
    float4 xa = *reinterpret_cast<const float4*>(X + i * SROW + scol);     // LDS broadcast
    float4 xb = *reinterpret_cast<const float4*>(X + i * SROW + scol + 4); // LDS broadcast
    float xs[TS] = {xa.x, xa.y, xa.z, xa.w, xb.x, xb.y, xb.z, xb.w};
#pragma unroll
    for (int s = 0; s < TS; ++s) {
      acc[s][0] = fmaf(xs[s], wv.x, acc[s][0]);
      acc[s][1] = fmaf(xs[s], wv.y, acc[s][1]);
      acc[s][2] = fmaf(xs[s], wv.z, acc[s][2]);
      acc[s][3] = fmaf(xs[s], wv.w, acc[s][3]);
    }
  }
}

// Y[l*4+j][scol+s] = relu(acc[s][j] + bias[l*4+j])
__device__ __forceinline__ void write_relu(float* __restrict__ Y,
                                           const float acc[TS][TN],
                                           const float* __restrict__ bias,
                                           int l, int scol) {
  float4 bv = reinterpret_cast<const float4*>(bias)[l];
  const float bb[TN] = {bv.x, bv.y, bv.z, bv.w};
#pragma unroll
  for (int j = 0; j < TN; ++j) {
    const int row = l * TN + j;
    float4 v0, v1;
    v0.x = fmaxf(acc[0][j] + bb[j], 0.f);
    v0.y = fmaxf(acc[1][j] + bb[j], 0.f);
    v0.z = fmaxf(acc[2][j] + bb[j], 0.f);
    v0.w = fmaxf(acc[3][j] + bb[j], 0.f);
    v1.x = fmaxf(acc[4][j] + bb[j], 0.f);
    v1.y = fmaxf(acc[5][j] + bb[j], 0.f);
    v1.z = fmaxf(acc[6][j] + bb[j], 0.f);
    v1.w = fmaxf(acc[7][j] + bb[j], 0.f);
    *reinterpret_cast<float4*>(Y + row * SROW + scol) = v0;
    *reinterpret_cast<float4*>(Y + row * SROW + scol + 4) = v1;
  }
}

__global__ __launch_bounds__(256, 2) void topdown_kernel(
    const float* __restrict__ towers, const float* __restrict__ aggregate,
    const float* __restrict__ M1w, const float* __restrict__ M1b,
    const float* __restrict__ M2w, const float* __restrict__ M2b,
    const float* __restrict__ M3w, const float* __restrict__ M3b,
    const float* __restrict__ O1w, const float* __restrict__ O1b,
    const float* __restrict__ O2w, const float* __restrict__ O2b,
    const float* __restrict__ O3w, const float* __restrict__ O3b,
    float* __restrict__ out) {
  extern __shared__ float sm[];
  float* Abuf = sm;            // current summary (256 x 32)
  float* Bbuf = sm + BUF;      // layer scratch   (256 x 32)
  float* Tbuf = sm + 2 * BUF;  // tower           (14  x 32)

  const int tid  = threadIdx.x;
  const int l    = tid & 63;
  const int w    = tid >> 6;
  const int scol = w * TS;
  const int n0   = blockIdx.x * NSAMP;

  // init summary = broadcast(aggregate)
  {
    float v = aggregate[tid];
    float4 vv = make_float4(v, v, v, v);
    float4* row = reinterpret_cast<float4*>(Abuf + tid * SROW);
#pragma unroll
    for (int q = 0; q < NSAMP / 4; ++q) row[q] = vv;
  }
  float prod[TS];
#pragma unroll
  for (int s = 0; s < TS; ++s) prod[s] = 1.f;

  float acc[TS][TN];

  for (int kk = 0; kk < KS; ++kk) {
    // stage tower slice k = KS-1-kk (the reference flips along K)
    {
      const int tbase = (KS - 1 - kk) * NIN;
      const int i  = tid & 15;
      const int sb = tid >> 4;  // 0..15
      if (i < NIN) {
        Tbuf[i * SROW + sb]      = towers[(n0 + sb) * (KS * NIN) + tbase + i];
        Tbuf[i * SROW + sb + 16] = towers[(n0 + sb + 16) * (KS * NIN) + tbase + i];
      }
    }
    __syncthreads();  // S1: tower + new summary (prev M3) visible

    // ---- O1: [A,T] -> B
    zero_acc(acc);
    gemm_part<NH>(acc, Abuf, O1w, 0, l, scol);
    gemm_part<NIN>(acc, Tbuf, O1w, NH, l, scol);
    write_relu(Bbuf, acc, O1b, l, scol);  // safe: all waves past S1 => prev M3 reads of B done
    __syncthreads();  // S2: B(O1) visible

    // ---- O2 + folded O3 + sigmoid + prod update (registers only)
    zero_acc(acc);
    gemm_part<NH>(acc, Bbuf, O2w, 0, l, scol);
    {
      float4 b2 = reinterpret_cast<const float4*>(O2b)[l];
      float4 o3 = reinterpret_cast<const float4*>(O3w)[l];
      float p[TS];
#pragma unroll
      for (int s = 0; s < TS; ++s) {
        float t = fmaxf(acc[s][0] + b2.x, 0.f) * o3.x;
        t = fmaf(fmaxf(acc[s][1] + b2.y, 0.f), o3.y, t);
        t = fmaf(fmaxf(acc[s][2] + b2.z, 0.f), o3.z, t);
        t = fmaf(fmaxf(acc[s][3] + b2.w, 0.f), o3.w, t);
        p[s] = t;
      }
#pragma unroll
      for (int off = 32; off > 0; off >>= 1) {
#pragma unroll
        for (int s = 0; s < TS; ++s) p[s] += __shfl_xor(p[s], off);
      }
      const float b3 = O3b[0];
#pragma unroll
      for (int s = 0; s < TS; ++s) {
        float z = p[s] + b3;
        prod[s] *= 1.f / (1.f + expf(-z));
      }
    }

    // ---- M1: [A,T] -> A (barrier between read and overwrite)
    zero_acc(acc);
    gemm_part<NH>(acc, Abuf, M1w, 0, l, scol);
    gemm_part<NIN>(acc, Tbuf, M1w, NH, l, scol);
    __syncthreads();  // S3: all waves done reading A (and T)
    write_relu(Abuf, acc, M1b, l, scol);
    __syncthreads();  // S4: A(M1) visible

    // ---- M2: A -> B (O2 readers of B all passed S3)
    zero_acc(acc);
    gemm_part<NH>(acc, Abuf, M2w, 0, l, scol);
    write_relu(Bbuf, acc, M2b, l, scol);
    __syncthreads();  // S5: B(M2) visible

    // ---- M3: B -> A (M2 readers of A all passed S5); next-iter S1 publishes
    zero_acc(acc);
    gemm_part<NH>(acc, Bbuf, M3w, 0, l, scol);
    write_relu(Abuf, acc, M3b, l, scol);
  }

  // every lane holds all 8 prods after the butterfly; lane s writes sample s
#pragma unroll
  for (int s = 0; s < TS; ++s)
    if (l == s) out[n0 + scol + s] = prod[s];
}

extern "C" void kernel_launch(void* const* d_in, const int* in_sizes, int n_in,
                              void* d_out, int out_size, void* d_ws, size_t ws_size,
                              hipStream_t stream) {
  const float* towers    = (const float*)d_in[0];
  const float* aggregate = (const float*)d_in[1];
  const float* M1w = (const float*)d_in[2];
  const float* M1b = (const float*)d_in[3];
  const float* M2w = (const float*)d_in[4];
  const float* M2b = (const float*)d_in[5];
  const float* M3w = (const float*)d_in[6];
  const float* M3b = (const float*)d_in[7];
  const float* O1w = (const float*)d_in[8];
  const float* O1b = (const float*)d_in[9];
  const float* O2w = (const float*)d_in[10];
  const float* O2b = (const float*)d_in[11];
  const float* O3w = (const float*)d_in[12];
  const float* O3b = (const float*)d_in[13];
  float* out = (float*)d_out;

  const int nblocks = out_size / NSAMP;  // 131072 / 32 = 4096

  // >64KB dynamic LDS needs the opt-in attribute (idempotent, capture-safe)
  hipFuncSetAttribute(reinterpret_cast<const void*>(&topdown_kernel),
                      hipFuncAttributeMaxDynamicSharedMemorySize,
                      (int)SMEM_BYTES);

  topdown_kernel<<<nblocks, 256, SMEM_BYTES, stream>>>(
      towers, aggregate, M1w, M1b, M2w, M2b, M3w, M3b,
      O1w, O1b, O2w, O2b, O3w, O3b, out);
}